// Round 5
// baseline (185.174 us; speedup 1.0000x reference)
//
#include <hip/hip_runtime.h>
#include <hip/hip_bf16.h>

#define B_   8
#define TQ_  100
#define TS_  100
#define E_   512
#define D_   512
#define K_   1024
#define M_   (B_*TQ_*TS_)   // 80000

#define BM   128            // M-tile per block (625 blocks)
#define BK   64             // K per step (16 steps)
#define NTHREADS 512        // 8 waves: 2M x 4N, wave tile 64x128

typedef __attribute__((ext_vector_type(4))) float f32x4;
typedef __attribute__((ext_vector_type(8))) short bf16x8;

__device__ __forceinline__ short f2bf(float f) {
  __hip_bfloat16 h = __float2bfloat16(f);
  return *reinterpret_cast<short*>(&h);
}

__device__ __forceinline__ float fast_tanh(float x) {
  float e = __expf(2.0f * x);
  return 1.0f - 2.0f / (e + 1.0f);
}

__device__ __forceinline__ void gld16(const void* g, void* l) {
  __builtin_amdgcn_global_load_lds(
      (const __attribute__((address_space(1))) unsigned int*)g,
      (__attribute__((address_space(3))) unsigned int*)l, 16, 0, 0);
}

// ---- prep: W1 [k=1024][n=512] f32 -> W1sw bf16 [n=512][k=1024], XOR-preswizzled
// within each 128B k-segment: element (n,k) at byte (k*2)^((n&7)<<4) of row n.
// gld16 then stages rows LINEARLY and ds_read at (n*128 + (kb^((n&7)<<4)))
// returns k-octet kb/16 of the staged 64-k chunk.  (R1/R3 layout: 0 conflicts.)
__global__ void prep_w1(const float* __restrict__ W1, short* __restrict__ W1sw) {
  int idx = blockIdx.x * 256 + threadIdx.x;   // over K_*D_
  int k = idx >> 9;
  int n = idx & (D_ - 1);
  int byte = (k * 2) ^ ((n & 7) << 4);
  W1sw[(size_t)n * K_ + (byte >> 1)] = f2bf(W1[idx]);
}

// ---- kernel 1: scores[m] = sum_n w2[n]*tanh(cat[m,:].W1[:,n] + b1[n]) ----
__launch_bounds__(NTHREADS, 2)
__global__ void scores_kernel(const float* __restrict__ src,
                              const float* __restrict__ tgt,
                              const short* __restrict__ W1sw,
                              const float* __restrict__ b1,
                              const float* __restrict__ w2,
                              float* __restrict__ scores) {
  __shared__ __align__(16) char Alds[2][BM * 128];   // 2 x 16 KB
  __shared__ __align__(16) char Blds[2][D_ * 128];   // 2 x 64 KB  (total 160 KB)

  const int tid  = threadIdx.x;
  const int wave = tid >> 6;
  const int lane = tid & 63;
  const int lr   = lane & 15;
  const int lg   = lane >> 4;
  const int wr   = wave >> 2;      // 0..1 -> rows wr*64..+64
  const int wc   = wave & 3;       // 0..3 -> cols wc*128..+128
  const int m0   = blockIdx.x * BM;

  f32x4 acc[4][8];
  #pragma unroll
  for (int i = 0; i < 4; i++)
    #pragma unroll
    for (int j = 0; j < 8; j++)
      acc[i][j] = (f32x4){0.f, 0.f, 0.f, 0.f};

  // A staging: thread -> row ra (4 thr/row), 16 consecutive floats at kaf
  const int ra  = tid >> 2;                 // 0..127
  const int kaf = (tid & 3) * 16;           // 0,16,32,48
  const int asw = (ra & 7) << 4;
  const size_t arow = (size_t)(m0 + ra) * E_;
  // B staging: 8 gld16; round j covers n = j*64 + lane-derived
  const size_t bgrow = (size_t)(tid >> 3) * 2048 + (size_t)(tid & 7) * 16;

  #define WAIT_LGKM0  { asm volatile("s_waitcnt lgkmcnt(0)" ::: "memory"); \
                        __builtin_amdgcn_sched_barrier(0); }
  #define BAR         __builtin_amdgcn_s_barrier()

  #define RD_B(BB, NI0, CUR)                                                   \
    _Pragma("unroll")                                                          \
    for (int u = 0; u < 2; u++) {                                              \
      int n = wc * 128 + ((NI0) + u) * 16 + lr;                                \
      _Pragma("unroll")                                                        \
      for (int kk = 0; kk < 2; kk++)                                           \
        BB[u][kk] = *(const bf16x8*)(Blds[CUR] + n * 128 +                     \
                        ((kk * 64 + lg * 16) ^ ((n & 7) << 4)));               \
    }

  #define MFMA8(BB, NI0)                                                       \
    { __builtin_amdgcn_s_setprio(1);                                           \
      _Pragma("unroll")                                                        \
      for (int kk = 0; kk < 2; kk++)                                           \
        _Pragma("unroll")                                                      \
        for (int mi = 0; mi < 4; mi++)                                         \
          _Pragma("unroll")                                                    \
          for (int u = 0; u < 2; u++)                                          \
            acc[mi][(NI0) + u] = __builtin_amdgcn_mfma_f32_16x16x32_bf16(      \
                a[mi][kk], BB[u][kk], acc[mi][(NI0) + u], 0, 0, 0);            \
      __builtin_amdgcn_s_setprio(0); }

  // prologue: stage tile 0 (B via gld16, A via reg+cvt), full drain
  {
    #pragma unroll
    for (int j = 0; j < 8; j++)
      gld16((const char*)W1sw + (size_t)j * 131072 + bgrow,
            Blds[0] + j * 8192 + wave * 1024);
    const float* Ap = src + arow + kaf;
    f32x4 r0 = *(const f32x4*)(Ap);
    f32x4 r1 = *(const f32x4*)(Ap + 4);
    f32x4 r2 = *(const f32x4*)(Ap + 8);
    f32x4 r3 = *(const f32x4*)(Ap + 12);
    bf16x8 w0, w1;
    w0[0]=f2bf(r0[0]); w0[1]=f2bf(r0[1]); w0[2]=f2bf(r0[2]); w0[3]=f2bf(r0[3]);
    w0[4]=f2bf(r1[0]); w0[5]=f2bf(r1[1]); w0[6]=f2bf(r1[2]); w0[7]=f2bf(r1[3]);
    w1[0]=f2bf(r2[0]); w1[1]=f2bf(r2[1]); w1[2]=f2bf(r2[2]); w1[3]=f2bf(r2[3]);
    w1[4]=f2bf(r3[0]); w1[5]=f2bf(r3[1]); w1[6]=f2bf(r3[2]); w1[7]=f2bf(r3[3]);
    int kb = kaf * 2;
    *(bf16x8*)(Alds[0] + ra * 128 + ( kb       ^ asw)) = w0;
    *(bf16x8*)(Alds[0] + ra * 128 + ((kb + 16) ^ asw)) = w1;
    asm volatile("s_waitcnt vmcnt(0) lgkmcnt(0)" ::: "memory");
    __builtin_amdgcn_sched_barrier(0);
    BAR;
  }

  for (int t = 0; t < 16; ++t) {
    const int cur = t & 1;
    const int nxt = cur ^ 1;
    const bool pf = (t < 15);
    const int kn  = (t + 1) * BK;       // next chunk's k base
    f32x4 r0, r1, r2, r3;
    bf16x8 a[4][2];

    // ---------- phase 0: read all A-frags + B ni{0,1}; issue A[t+1] ----------
    #pragma unroll
    for (int mi = 0; mi < 4; mi++) {
      int row = wr * 64 + mi * 16 + lr;
      #pragma unroll
      for (int kk = 0; kk < 2; kk++)
        a[mi][kk] = *(const bf16x8*)(Alds[cur] + row * 128 +
                        ((kk * 64 + lg * 16) ^ ((row & 7) << 4)));
    }
    {
      bf16x8 bb[2][2];
      RD_B(bb, 0, cur);
      if (pf) {
        const float* Ap = ((kn < E_) ? src : tgt) + arow + (kn & (E_ - 1)) + kaf;
        r0 = *(const f32x4*)(Ap);
        r1 = *(const f32x4*)(Ap + 4);
        r2 = *(const f32x4*)(Ap + 8);
        r3 = *(const f32x4*)(Ap + 12);
      }
      BAR; WAIT_LGKM0;
      MFMA8(bb, 0);
      BAR;
    }
    // ---------- phase 1: B ni{2,3}; issue gld16 B[t+1] j=0..3 ----------
    {
      bf16x8 bb[2][2];
      RD_B(bb, 2, cur);
      if (pf) {
        #pragma unroll
        for (int j = 0; j < 4; j++)
          gld16((const char*)W1sw + (size_t)j * 131072 + (size_t)kn * 2 + bgrow,
                Blds[nxt] + j * 8192 + wave * 1024);
      }
      BAR; WAIT_LGKM0;
      MFMA8(bb, 2);
      BAR;
    }
    // ---------- phase 2: B ni{4,5}; issue gld16 B[t+1] j=4..7 ----------
    {
      bf16x8 bb[2][2];
      RD_B(bb, 4, cur);
      if (pf) {
        #pragma unroll
        for (int j = 4; j < 8; j++)
          gld16((const char*)W1sw + (size_t)j * 131072 + (size_t)kn * 2 + bgrow,
                Blds[nxt] + j * 8192 + wave * 1024);
      }
      BAR; WAIT_LGKM0;
      MFMA8(bb, 4);
      BAR;
    }
    // ---------- phase 3: B ni{6,7}; cvt+write A[t+1]; drain gld16 ----------
    {
      bf16x8 bb[2][2];
      RD_B(bb, 6, cur);
      if (pf) {
        asm volatile("s_waitcnt vmcnt(8)" ::: "memory");   // 4 A-loads done; 8 gld16 in flight
        __builtin_amdgcn_sched_barrier(0);
        bf16x8 w0, w1;
        w0[0]=f2bf(r0[0]); w0[1]=f2bf(r0[1]); w0[2]=f2bf(r0[2]); w0[3]=f2bf(r0[3]);
        w0[4]=f2bf(r1[0]); w0[5]=f2bf(r1[1]); w0[6]=f2bf(r1[2]); w0[7]=f2bf(r1[3]);
        w1[0]=f2bf(r2[0]); w1[1]=f2bf(r2[1]); w1[2]=f2bf(r2[2]); w1[3]=f2bf(r2[3]);
        w1[4]=f2bf(r3[0]); w1[5]=f2bf(r3[1]); w1[6]=f2bf(r3[2]); w1[7]=f2bf(r3[3]);
        int kb = kaf * 2;
        *(bf16x8*)(Alds[nxt] + ra * 128 + ( kb       ^ asw)) = w0;
        *(bf16x8*)(Alds[nxt] + ra * 128 + ((kb + 16) ^ asw)) = w1;
      }
      BAR; WAIT_LGKM0;
      MFMA8(bb, 6);
      // counted drain: B[t+1] gld16s issued >=2 phases ago; A ds_writes retired
      asm volatile("s_waitcnt vmcnt(0) lgkmcnt(0)" ::: "memory");
      __builtin_amdgcn_sched_barrier(0);
      BAR;
    }
  }

  // ---- epilogue: scores[m] = sum_n w2[n]*tanh(h[m,n]+b1[n]) ----
  float* s_sc = (float*)Alds;   // done with A buffers
  if (tid < BM) s_sc[tid] = 0.0f;
  __syncthreads();

  float b1v[8], w2v[8];
  #pragma unroll
  for (int ni = 0; ni < 8; ni++) {
    int n = wc * 128 + ni * 16 + lr;
    b1v[ni] = b1[n];
    w2v[ni] = w2[n];
  }
  #pragma unroll
  for (int mi = 0; mi < 4; mi++) {
    #pragma unroll
    for (int r = 0; r < 4; r++) {
      float p = 0.0f;
      #pragma unroll
      for (int ni = 0; ni < 8; ni++)
        p += fast_tanh(acc[mi][ni][r] + b1v[ni]) * w2v[ni];
      p += __shfl_xor(p, 1);
      p += __shfl_xor(p, 2);
      p += __shfl_xor(p, 4);
      p += __shfl_xor(p, 8);
      if (lr == 0) atomicAdd(&s_sc[wr * 64 + mi * 16 + lg * 4 + r], p);
    }
  }
  __syncthreads();
  if (tid < BM) scores[m0 + tid] = s_sc[tid];
}

// ---- kernel 2: mask, softmax over s, weights out, weighted sum over src ----
__global__ void softmax_wsum(const float* __restrict__ src,
                             const float* __restrict__ mask,
                             const float* __restrict__ scores,
                             float* __restrict__ out) {
  const int row = blockIdx.x;     // b*TQ+q, 0..799
  const int tid = threadIdx.x;    // 512 threads
  __shared__ float s_e[TS_];

  float v = 0.0f;
  if (tid < TS_) {
    v = scores[row * TS_ + tid] * mask[row * TS_ + tid];
    s_e[tid] = v;
  }
  __syncthreads();
  float mx = -3.0e38f;
  for (int s = 0; s < TS_; s++) mx = fmaxf(mx, s_e[s]);
  __syncthreads();
  if (tid < TS_) s_e[tid] = __expf(v - mx);
  __syncthreads();
  float sum = 0.0f;
  for (int s = 0; s < TS_; s++) sum += s_e[s];
  const float inv = 1.0f / sum;

  float* out_attn = out;                          // [800][512]
  float* out_w    = out + (size_t)B_ * TQ_ * E_;  // [800][100]
  if (tid < TS_) out_w[row * TS_ + tid] = s_e[tid] * inv;

  const float* sp = src + (size_t)row * TS_ * E_ + tid;
  float acc = 0.0f;
  #pragma unroll 4
  for (int s = 0; s < TS_; s++) acc = fmaf(s_e[s], sp[(size_t)s * E_], acc);
  out_attn[row * E_ + tid] = acc * inv;
}

extern "C" void kernel_launch(void* const* d_in, const int* in_sizes, int n_in,
                              void* d_out, int out_size, void* d_ws, size_t ws_size,
                              hipStream_t stream) {
  const float* src  = (const float*)d_in[0];
  const float* tgt  = (const float*)d_in[1];
  const float* mask = (const float*)d_in[2];
  const float* W1   = (const float*)d_in[3];
  const float* b1   = (const float*)d_in[4];
  const float* w2   = (const float*)d_in[5];

  short* W1sw   = (short*)d_ws;                                // 1 MB
  float* scores = (float*)((char*)d_ws + (size_t)D_ * K_ * 2); // 80000 f32

  float* out = (float*)d_out;

  hipLaunchKernelGGL(prep_w1, dim3((K_ * D_) / 256), dim3(256), 0, stream, W1, W1sw);
  hipLaunchKernelGGL(scores_kernel, dim3(M_ / BM), dim3(NTHREADS), 0, stream,
                     src, tgt, W1sw, b1, w2, scores);
  hipLaunchKernelGGL(softmax_wsum, dim3(B_ * TQ_), dim3(512), 0, stream,
                     src, mask, scores, out);
}